// Round 3
// baseline (624.388 us; speedup 1.0000x reference)
//
#include <hip/hip_runtime.h>
#include <hip/hip_cooperative_groups.h>
#include <limits.h>

namespace cg = cooperative_groups;

#define HH 128
#define WW_ 128
#define HW 16384
#define NB 16
#define CF 192
#define H2 64
#define W2 64

#define SH 16          // stripe height
#define NSPI 8         // stripes per image
#define NST 128        // total stripe blocks
#define SC 512         // max components per 16x128 stripe
#define NCI 4096       // component handles per image = NSPI*SC
#define NLRUN 1024     // local run-id slots = SH*64
#define NBLK 256       // cooperative grid: 1 block per CU
#define NTHR 1024

typedef float vf4 __attribute__((ext_vector_type(4)));
typedef unsigned long long ull;

// ---------------------------------------------------------------------------
// Union-find on an LDS parent array. Links always go high->low id -> chains
// strictly decrease -> concurrent path halving is safe and terminating.
// ---------------------------------------------------------------------------

__device__ inline int uf_find(int* par, int x) {
    volatile int* vp = (volatile int*)par;
    int p = vp[x];
    while (p != x) {
        int g = vp[p];
        vp[x] = g;      // path halving: writes an ancestor, safe under races
        x = g;
        p = vp[x];
    }
    return x;
}

__device__ inline void uf_union(int* par, int a, int b) {
    int ra = uf_find(par, a);
    int rb = uf_find(par, b);
    while (ra != rb) {
        if (ra < rb) { int t = ra; ra = rb; rb = t; }   // link larger -> smaller
        int old = atomicCAS(&par[ra], ra, rb);
        if (old == ra) return;
        ra = uf_find(par, old);
        rb = uf_find(par, rb);
    }
}

// ---------------------------------------------------------------------------
// 128-bit row mask helpers (lo = cols 0..63, hi = cols 64..127)
// ---------------------------------------------------------------------------

__device__ inline int getbit2(ull lo, ull hi, int c) {
    return (int)(((c < 64) ? (lo >> c) : (hi >> (c - 64))) & 1ULL);
}

__device__ inline int leading_ones(ull v) {
    ull nv = ~v;
    return (nv == 0ULL) ? 64 : __clzll(nv);
}

// column of the start of the fg run containing column c (bit c must be set)
__device__ inline int run_start_col(ull lo, ull hi, int c) {
    if (c < 64) {
        int ones = leading_ones(lo << (63 - c));   // consecutive ones ending at c
        return c - ones + 1;
    }
    int ones = leading_ones(hi << (127 - c));
    int rs = c - ones + 1;
    if (rs == 64) rs -= leading_ones(lo);          // run crosses the 64 boundary
    return rs;
}

// 0-based index of the run starting at column cs (cs must be a run start)
__device__ inline int run_index(ull rs_lo, ull rs_hi, int cs) {
    if (cs < 64)  return __popcll(rs_lo & ((1ULL << cs) - 1ULL));
    if (cs == 64) return __popcll(rs_lo);
    return __popcll(rs_lo) + __popcll(rs_hi & ((1ULL << (cs - 64)) - 1ULL));
}

__device__ inline void top3_ins(float s, int id, int x,
    float& s0, float& s1, float& s2,
    int& i0, int& i1, int& i2,
    int& x0, int& x1, int& x2)
{
    if (x < 0) return;
    if (s > s0 || (s == s0 && id < i0)) {
        s2 = s1; i2 = i1; x2 = x1;
        s1 = s0; i1 = i0; x1 = x0;
        s0 = s;  i0 = id; x0 = x;
    } else if (s > s1 || (s == s1 && id < i1)) {
        s2 = s1; i2 = i1; x2 = x1;
        s1 = s;  i1 = id; x1 = x;
    } else if (s > s2 || (s == s2 && id < i2)) {
        s2 = s;  i2 = id; x2 = x;
    }
}

// ---------------------------------------------------------------------------
// LDS overlay: phase A (stripe CCL, ~18.5 KB) and phase B (image merge,
// ~128.6 KB) never live simultaneously -> union. Static size ~128.6 KB
// -> 1 block/CU, which matches the cooperative grid of 256 blocks.
// ---------------------------------------------------------------------------

struct SmA {
    ull rowm[SH][2];
    unsigned char m8[256];
    int parent[NLRUN];
    int   lcnt[SC];
    float lconf[SC];
    int lminr[SC], lmaxr[SC], lminc[SC], lmaxc[SC], lmaxid[SC];
    int snloc;
};

struct SmB {
    int parent2[NCI];
    int   cnt2[NCI];
    float conf2[NCI];
    int minr2[NCI], maxr2[NCI], minc2[NCI], maxc2[NCI], maxid2[NCI];
    int sK;
    float wss[48];
    int wid_[48], wrx[48];
};

union Sm { SmA a; SmB b; };

// ---------------------------------------------------------------------------
// Single cooperative kernel.
//  Phase A (blocks 0..127): per-stripe run-based union-find CCL + stats.
//  Phase B (blocks 0..15):  per-image boundary merge + top-3 + bbox.
//  Phase C (all blocks):    grid-stride nearest-neighbor crop gather.
// Union set / tie-breaks identical to the 3-kernel version.
// ---------------------------------------------------------------------------

__global__ __launch_bounds__(NTHR) void fused_kernel(
    const float* __restrict__ prob, const float* __restrict__ feat,
    float* __restrict__ out, int* __restrict__ bbox,
    int* __restrict__ nlocg, int* __restrict__ gcnt, float* __restrict__ gconf,
    int* __restrict__ gminr, int* __restrict__ gmaxr,
    int* __restrict__ gminc, int* __restrict__ gmaxc,
    int* __restrict__ gmaxid, int* __restrict__ brun, ull* __restrict__ bmask)
{
    __shared__ Sm sm;
    cg::grid_group grid = cg::this_grid();
    const int blk = blockIdx.x;
    const int tid = threadIdx.x;

    // ================= Phase A: stripe CCL (blocks 0..127) =================
    if (blk < NST) {
        SmA& A = sm.a;
        const int b = blk >> 3, s = blk & 7;
        const int row0 = s * SH;
        if (tid == 0) A.snloc = 0;

        int mask8 = 0;
        vf4 va = {0, 0, 0, 0}, vb = {0, 0, 0, 0};
        if (tid < 256) {
            // P0: 8 pixels per thread into registers (row = tid>>4, 8-col win)
            int row = tid >> 4, w0 = (tid & 15) * 8;
            const float* p = prob + (size_t)b * HW + (size_t)((row0 + row) << 7) + w0;
            va = *(const vf4*)p;
            vb = *(const vf4*)(p + 4);
            mask8 |= (va.x > 0.5f) << 0; mask8 |= (va.y > 0.5f) << 1;
            mask8 |= (va.z > 0.5f) << 2; mask8 |= (va.w > 0.5f) << 3;
            mask8 |= (vb.x > 0.5f) << 4; mask8 |= (vb.y > 0.5f) << 5;
            mask8 |= (vb.z > 0.5f) << 6; mask8 |= (vb.w > 0.5f) << 7;
            A.m8[tid] = (unsigned char)mask8;
        }
        for (int j = tid; j < SC; j += NTHR) {
            A.lcnt[j] = 0; A.lconf[j] = 0.f;
            A.lminr[j] = INT_MAX; A.lmaxr[j] = -1;
            A.lminc[j] = INT_MAX; A.lmaxc[j] = -1;
            A.lmaxid[j] = 0;
        }
        __syncthreads();
        if (tid < 32) {                        // assemble 64-bit half-row masks
            int r = tid >> 1, half = tid & 1;
            ull v = 0;
            #pragma unroll
            for (int k2 = 0; k2 < 8; ++k2)
                v |= (ull)A.m8[(r << 4) + (half << 3) + k2] << (k2 * 8);
            A.rowm[r][half] = v;
        }
        __syncthreads();

        // P1: parent self-init (NLRUN == NTHR: one slot per thread)
        {
            int rid = tid;
            int r = rid >> 6;
            ull lo = A.rowm[r][0], hi = A.rowm[r][1];
            ull rs_lo = lo & ~(lo << 1);
            ull rs_hi = hi & ~((hi << 1) | (lo >> 63));
            int nruns = __popcll(rs_lo) + __popcll(rs_hi);
            if ((rid & 63) < nruns) A.parent[rid] = rid;
        }
        __syncthreads();

        // P2: vertical unions inside the stripe (local rows 1..15)
        for (int i = tid; i < (SH - 1) * 128; i += NTHR) {
            int r = 1 + (i >> 7), c = i & 127;
            ull lo = A.rowm[r][0], hi = A.rowm[r][1];
            if (!getbit2(lo, hi, c)) continue;
            ull ulo = A.rowm[r - 1][0], uhi = A.rowm[r - 1][1];
            int l  = (c > 0)   ? getbit2(lo, hi, c - 1) : 0;
            int rt = (c < 127) ? getbit2(lo, hi, c + 1) : 0;
            int up = getbit2(ulo, uhi, c);
            int ul = (c > 0)   ? getbit2(ulo, uhi, c - 1) : 0;
            int ur = (c < 127) ? getbit2(ulo, uhi, c + 1) : 0;
            bool u1 = up && !(l && ul);          // leftmost-contact dedup
            bool u2 = !up && ul && !l;
            bool u3 = !up && ur && !rt;
            if (!(u1 | u2 | u3)) continue;
            ull rs_lo = lo & ~(lo << 1),   rs_hi = hi & ~((hi << 1) | (lo >> 63));
            ull urs_lo = ulo & ~(ulo << 1), urs_hi = uhi & ~((uhi << 1) | (ulo >> 63));
            int cs = run_start_col(lo, hi, c);
            int rid = (r << 6) + run_index(rs_lo, rs_hi, cs);
            int ub = (r - 1) << 6;
            if (u1) uf_union(A.parent, rid, ub + run_index(urs_lo, urs_hi, run_start_col(ulo, uhi, c)));
            if (u2) uf_union(A.parent, rid, ub + run_index(urs_lo, urs_hi, run_start_col(ulo, uhi, c - 1)));
            if (u3) uf_union(A.parent, rid, ub + run_index(urs_lo, urs_hi, run_start_col(ulo, uhi, c + 1)));
        }
        __syncthreads();

        // P3: flatten
        {
            int rid = tid;
            int r = rid >> 6;
            ull lo = A.rowm[r][0], hi = A.rowm[r][1];
            ull rs_lo = lo & ~(lo << 1);
            ull rs_hi = hi & ~((hi << 1) | (lo >> 63));
            int nruns = __popcll(rs_lo) + __popcll(rs_hi);
            if ((rid & 63) < nruns) A.parent[rid] = uf_find(A.parent, rid);
        }
        __syncthreads();
        // P3b: roots claim dense local indices
        {
            int rid = tid;
            int r = rid >> 6;
            ull lo = A.rowm[r][0], hi = A.rowm[r][1];
            ull rs_lo = lo & ~(lo << 1);
            ull rs_hi = hi & ~((hi << 1) | (lo >> 63));
            int nruns = __popcll(rs_lo) + __popcll(rs_hi);
            if ((rid & 63) < nruns && A.parent[rid] == rid) {
                int idx = atomicAdd(&A.snloc, 1);
                A.parent[rid] = NLRUN + idx;
            }
        }
        __syncthreads();

        // P4: per-thread window stats from registers (each pixel counted once)
        if (tid < 256) {
            int row = tid >> 4, w0 = (tid & 15) * 8;
            ull lo = A.rowm[row][0], hi = A.rowm[row][1];
            ull rs_lo = lo & ~(lo << 1);
            ull rs_hi = hi & ~((hi << 1) | (lo >> 63));
            const float vv[8] = {va.x, va.y, va.z, va.w, vb.x, vb.y, vb.z, vb.w};
            const int imr = row0 + row;
            int curIdx = -1, aCnt = 0, aMinc = 0, aMaxc = 0, aMaxid = 0;
            float aConf = 0.f;
            bool prevfg = false;
            #pragma unroll
            for (int j = 0; j < 8; ++j) {
                bool fg = (mask8 >> j) & 1;
                if (fg) {
                    int c = w0 + j;
                    if (!prevfg) {                 // new window-segment: resolve comp
                        int cs = run_start_col(lo, hi, c);
                        int rid = (row << 6) + run_index(rs_lo, rs_hi, cs);
                        int v = A.parent[rid];
                        int idx = (v >= NLRUN) ? v - NLRUN : A.parent[v] - NLRUN;
                        if (idx != curIdx) {
                            if (curIdx >= 0) {
                                atomicAdd(&A.lcnt[curIdx], aCnt);
                                atomicAdd(&A.lconf[curIdx], aConf);
                                atomicMin(&A.lminr[curIdx], imr);
                                atomicMax(&A.lmaxr[curIdx], imr);
                                atomicMin(&A.lminc[curIdx], aMinc);
                                atomicMax(&A.lmaxc[curIdx], aMaxc);
                                atomicMax(&A.lmaxid[curIdx], aMaxid);
                            }
                            curIdx = idx; aCnt = 0; aConf = 0.f;
                            aMinc = c; aMaxc = c; aMaxid = 0;
                        }
                    }
                    aCnt++; aConf += vv[j]; aMaxc = c;
                    aMaxid = (imr << 7) + c + 1;
                }
                prevfg = fg;
            }
            if (curIdx >= 0) {
                atomicAdd(&A.lcnt[curIdx], aCnt);
                atomicAdd(&A.lconf[curIdx], aConf);
                atomicMin(&A.lminr[curIdx], imr);
                atomicMax(&A.lmaxr[curIdx], imr);
                atomicMin(&A.lminc[curIdx], aMinc);
                atomicMax(&A.lmaxc[curIdx], aMaxc);
                atomicMax(&A.lmaxid[curIdx], aMaxid);
            }
        }
        __syncthreads();

        // P5: export component table + boundary maps
        const int nl = A.snloc;
        for (int j = tid; j < nl; j += NTHR) {
            int d = (blk << 9) + j;
            gcnt[d] = A.lcnt[j];  gconf[d] = A.lconf[j];
            gminr[d] = A.lminr[j]; gmaxr[d] = A.lmaxr[j];
            gminc[d] = A.lminc[j]; gmaxc[d] = A.lmaxc[j];
            gmaxid[d] = A.lmaxid[j];
        }
        if (tid == 0) nlocg[blk] = nl;
        if (tid < 128) {
            int br = tid >> 6;                 // 0: local row 0, 1: local row 15
            int j = tid & 63;
            int r = br ? (SH - 1) : 0;
            ull lo = A.rowm[r][0], hi = A.rowm[r][1];
            ull rs_lo = lo & ~(lo << 1);
            ull rs_hi = hi & ~((hi << 1) | (lo >> 63));
            int nruns = __popcll(rs_lo) + __popcll(rs_hi);
            if (j < nruns) {
                int rid = (r << 6) + j;
                int v = A.parent[rid];
                brun[(blk << 7) + (br << 6) + j] = (v >= NLRUN) ? v - NLRUN : A.parent[v] - NLRUN;
            }
            if (j == 0) {
                bmask[(blk << 2) + (br << 1) + 0] = lo;
                bmask[(blk << 2) + (br << 1) + 1] = hi;
            }
        }
    }

    __threadfence();
    grid.sync();
    __threadfence();

    // ================= Phase B: per-image merge (blocks 0..15) =============
    if (blk < NB) {
        SmB& B = sm.b;
        const int b = blk;
        if (tid == 0) B.sK = 0;
        for (int i = tid; i < NCI; i += NTHR) { B.parent2[i] = i; B.cnt2[i] = 0; }
        __syncthreads();

        // load stripe component tables into handle space s*512+j
        for (int s = 0; s < NSPI; ++s) {
            int g = (b << 3) + s;
            int n = nlocg[g];
            for (int j = tid; j < n; j += NTHR) {
                int d = (s << 9) + j, e = (g << 9) + j;
                B.cnt2[d] = gcnt[e];  B.conf2[d] = gconf[e];
                B.minr2[d] = gminr[e]; B.maxr2[d] = gmaxr[e];
                B.minc2[d] = gminc[e]; B.maxc2[d] = gmaxc[e];
                B.maxid2[d] = gmaxid[e];
            }
        }
        __syncthreads();

        // boundary unions: boundary k joins stripe k-1 (row 15) with stripe k
        for (int i = tid; i < 7 * 128; i += NTHR) {
            int k = 1 + (i >> 7), c = i & 127;
            int gLo = (b << 3) + k, gUp = gLo - 1;
            ull lo = bmask[(gLo << 2) + 0], hi = bmask[(gLo << 2) + 1];
            if (!getbit2(lo, hi, c)) continue;
            ull ulo = bmask[(gUp << 2) + 2], uhi = bmask[(gUp << 2) + 3];
            int l  = (c > 0)   ? getbit2(lo, hi, c - 1) : 0;
            int rt = (c < 127) ? getbit2(lo, hi, c + 1) : 0;
            int up = getbit2(ulo, uhi, c);
            int ul = (c > 0)   ? getbit2(ulo, uhi, c - 1) : 0;
            int ur = (c < 127) ? getbit2(ulo, uhi, c + 1) : 0;
            bool u1 = up && !(l && ul);
            bool u2 = !up && ul && !l;
            bool u3 = !up && ur && !rt;
            if (!(u1 | u2 | u3)) continue;
            ull rs_lo = lo & ~(lo << 1),   rs_hi = hi & ~((hi << 1) | (lo >> 63));
            ull urs_lo = ulo & ~(ulo << 1), urs_hi = uhi & ~((uhi << 1) | (ulo >> 63));
            int cs = run_start_col(lo, hi, c);
            int myid = (k << 9) + brun[(gLo << 7) + run_index(rs_lo, rs_hi, cs)];
            int ubase = (k - 1) << 9;
            if (u1) uf_union(B.parent2, myid, ubase + brun[(gUp << 7) + 64 + run_index(urs_lo, urs_hi, run_start_col(ulo, uhi, c))]);
            if (u2) uf_union(B.parent2, myid, ubase + brun[(gUp << 7) + 64 + run_index(urs_lo, urs_hi, run_start_col(ulo, uhi, c - 1))]);
            if (u3) uf_union(B.parent2, myid, ubase + brun[(gUp << 7) + 64 + run_index(urs_lo, urs_hi, run_start_col(ulo, uhi, c + 1))]);
        }
        __syncthreads();

        // fold non-root stats into roots
        for (int i = tid; i < NCI; i += NTHR) {
            if (B.cnt2[i] > 0) {
                int r = uf_find(B.parent2, i);
                if (r != i) {
                    atomicAdd(&B.cnt2[r], B.cnt2[i]);   atomicAdd(&B.conf2[r], B.conf2[i]);
                    atomicMin(&B.minr2[r], B.minr2[i]); atomicMax(&B.maxr2[r], B.maxr2[i]);
                    atomicMin(&B.minc2[r], B.minc2[i]); atomicMax(&B.maxc2[r], B.maxc2[i]);
                    atomicMax(&B.maxid2[r], B.maxid2[i]);
                }
            }
        }
        __syncthreads();

        // top-3 by (mean_conf desc, maxid asc) over roots; K = root count
        float s0 = -INFINITY, s1 = -INFINITY, s2 = -INFINITY;
        int i0 = INT_MAX, i1 = INT_MAX, i2 = INT_MAX;
        int x0 = -1, x1 = -1, x2 = -1;
        int kc = 0;
        for (int i = tid; i < NCI; i += NTHR) {
            if (B.parent2[i] == i && B.cnt2[i] > 0) {
                ++kc;
                float sc = B.conf2[i] / (float)B.cnt2[i];
                top3_ins(sc, B.maxid2[i], i, s0, s1, s2, i0, i1, i2, x0, x1, x2);
            }
        }
        for (int off = 32; off; off >>= 1) kc += __shfl_xor(kc, off);
        if ((tid & 63) == 0) atomicAdd(&B.sK, kc);
        for (int off = 32; off; off >>= 1) {
            float bs0 = __shfl_xor(s0, off), bs1 = __shfl_xor(s1, off), bs2 = __shfl_xor(s2, off);
            int bi0 = __shfl_xor(i0, off), bi1 = __shfl_xor(i1, off), bi2 = __shfl_xor(i2, off);
            int bx0 = __shfl_xor(x0, off), bx1 = __shfl_xor(x1, off), bx2 = __shfl_xor(x2, off);
            top3_ins(bs0, bi0, bx0, s0, s1, s2, i0, i1, i2, x0, x1, x2);
            top3_ins(bs1, bi1, bx1, s0, s1, s2, i0, i1, i2, x0, x1, x2);
            top3_ins(bs2, bi2, bx2, s0, s1, s2, i0, i1, i2, x0, x1, x2);
        }
        if ((tid & 63) == 0) {
            int w = tid >> 6;
            B.wss[w * 3 + 0] = s0; B.wid_[w * 3 + 0] = i0; B.wrx[w * 3 + 0] = x0;
            B.wss[w * 3 + 1] = s1; B.wid_[w * 3 + 1] = i1; B.wrx[w * 3 + 1] = x1;
            B.wss[w * 3 + 2] = s2; B.wid_[w * 3 + 2] = i2; B.wrx[w * 3 + 2] = x2;
        }
        __syncthreads();

        if (tid == 0) {
            float t0 = -INFINITY, t1 = -INFINITY, t2 = -INFINITY;
            int ti0 = INT_MAX, ti1 = INT_MAX, ti2 = INT_MAX;
            int tx0 = -1, tx1 = -1, tx2 = -1;
            for (int t = 0; t < 48; ++t)
                top3_ins(B.wss[t], B.wid_[t], B.wrx[t], t0, t1, t2, ti0, ti1, ti2, tx0, tx1, tx2);
            int K = B.sK;
            int roots[3];
            if (K >= 3)      { roots[0] = tx0; roots[1] = tx1; roots[2] = tx2; }
            else if (K == 2) { roots[0] = tx0; roots[1] = tx0; roots[2] = tx1; }
            else             { roots[0] = tx0; roots[1] = tx0; roots[2] = tx0; }
            for (int slot = 0; slot < 3; ++slot) {
                int mr, h, mc, w;
                if (K == 0) { mr = 0; h = HH; mc = 0; w = WW_; }
                else {
                    int rt = roots[slot];
                    mr = B.minr2[rt]; h = B.maxr2[rt] + 1 - mr;
                    mc = B.minc2[rt]; w = B.maxc2[rt] + 1 - mc;
                }
                int* o = bbox + (b * 3 + slot) * 4;
                o[0] = mr; o[1] = h; o[2] = mc; o[3] = w;
            }
        }
    }

    __threadfence();
    grid.sync();
    __threadfence();

    // ================= Phase C: crop gather (all blocks) ===================
    const int total4 = NB * 3 * CF * H2 * (W2 / 4);   // 9,437,184 (36 iters exact)
    for (int gid = blk * NTHR + tid; gid < total4; gid += NBLK * NTHR) {
        const int x4 = gid & 15;
        const int y  = (gid >> 4) & 63;
        const int t  = gid >> 10;        // (b*3+slot)*192 + c, 0..9215
        const int c  = t % CF;
        const int bs = t / CF;           // b*3+slot, 0..47
        const int* bb = bbox + bs * 4;
        const int mr = bb[0], h = bb[1], mc = bb[2], w = bb[3];
        const int r = mr + ((y * h) >> 6);
        const int bimg = bs / 3;
        const float* row = feat + (((size_t)bimg * CF + c) * HH + r) * WW_;
        const int x = x4 * 4;
        vf4 v;
        v.x = row[mc + (((x + 0) * w) >> 6)];
        v.y = row[mc + (((x + 1) * w) >> 6)];
        v.z = row[mc + (((x + 2) * w) >> 6)];
        v.w = row[mc + (((x + 3) * w) >> 6)];
        __builtin_nontemporal_store(v, (vf4*)out + gid);  // streaming store
    }
}

// ---------------------------------------------------------------------------

extern "C" void kernel_launch(void* const* d_in, const int* in_sizes, int n_in,
                              void* d_out, int out_size, void* d_ws, size_t ws_size,
                              hipStream_t stream) {
    const float* prob = (const float*)d_in[0];   // [16,1,128,128]
    const float* feat = (const float*)d_in[1];   // [16,192,128,128]
    float* out = (float*)d_out;                  // [16,576,64,64]

    int* ws = (int*)d_ws;
    int* bbox   = ws;                            // 192 ints
    int* nlocg  = ws + 192;                      // 128
    int* gcnt   = ws + 320;                      // 7 arrays x 128*512
    float* gconf = (float*)(ws + 320 + 1 * 65536);
    int* gminr  = ws + 320 + 2 * 65536;
    int* gmaxr  = ws + 320 + 3 * 65536;
    int* gminc  = ws + 320 + 4 * 65536;
    int* gmaxc  = ws + 320 + 5 * 65536;
    int* gmaxid = ws + 320 + 6 * 65536;
    int* brun   = ws + 320 + 7 * 65536;          // 128*2*64
    ull* bmask  = (ull*)(ws + 320 + 7 * 65536 + 16384);  // 128*2*2 ulls

    void* args[] = {
        (void*)&prob, (void*)&feat, (void*)&out, (void*)&bbox,
        (void*)&nlocg, (void*)&gcnt, (void*)&gconf,
        (void*)&gminr, (void*)&gmaxr, (void*)&gminc, (void*)&gmaxc,
        (void*)&gmaxid, (void*)&brun, (void*)&bmask
    };
    hipLaunchCooperativeKernel((const void*)fused_kernel,
                               dim3(NBLK), dim3(NTHR), args, 0, stream);
}

// Round 4
// 371.486 us; speedup vs baseline: 1.6808x; 1.6808x over previous
//
#include <hip/hip_runtime.h>
#include <limits.h>

#define HH 128
#define WW_ 128
#define HW 16384
#define NB 16
#define CF 192
#define H2 64
#define W2 64

#define SH 16          // stripe height
#define NSPI 8         // stripes per image
#define NST 128        // total stripe blocks
#define SC 512         // max components per 16x128 stripe
#define NCI 4096       // component handles per image = NSPI*SC
#define NLRUN 1024     // local run-id slots = SH*64

#define CROP_BLKS 2304 // 2304 blocks * 1024 thr * 4 vf4 = 9,437,184 stores

typedef float vf4 __attribute__((ext_vector_type(4)));
typedef unsigned long long ull;

// ---------------------------------------------------------------------------
// Union-find on an LDS parent array. Links always go high->low id -> chains
// strictly decrease -> concurrent path halving is safe and terminating.
// ---------------------------------------------------------------------------

__device__ inline int uf_find(int* par, int x) {
    volatile int* vp = (volatile int*)par;
    int p = vp[x];
    while (p != x) {
        int g = vp[p];
        vp[x] = g;      // path halving: writes an ancestor, safe under races
        x = g;
        p = vp[x];
    }
    return x;
}

__device__ inline void uf_union(int* par, int a, int b) {
    int ra = uf_find(par, a);
    int rb = uf_find(par, b);
    while (ra != rb) {
        if (ra < rb) { int t = ra; ra = rb; rb = t; }   // link larger -> smaller
        int old = atomicCAS(&par[ra], ra, rb);
        if (old == ra) return;
        ra = uf_find(par, old);
        rb = uf_find(par, rb);
    }
}

// ---------------------------------------------------------------------------
// 128-bit row mask helpers (lo = cols 0..63, hi = cols 64..127)
// ---------------------------------------------------------------------------

__device__ inline int getbit2(ull lo, ull hi, int c) {
    return (int)(((c < 64) ? (lo >> c) : (hi >> (c - 64))) & 1ULL);
}

__device__ inline int leading_ones(ull v) {
    ull nv = ~v;
    return (nv == 0ULL) ? 64 : __clzll(nv);
}

// column of the start of the fg run containing column c (bit c must be set)
__device__ inline int run_start_col(ull lo, ull hi, int c) {
    if (c < 64) {
        int ones = leading_ones(lo << (63 - c));   // consecutive ones ending at c
        return c - ones + 1;
    }
    int ones = leading_ones(hi << (127 - c));
    int rs = c - ones + 1;
    if (rs == 64) rs -= leading_ones(lo);          // run crosses the 64 boundary
    return rs;
}

// 0-based index of the run starting at column cs (cs must be a run start)
__device__ inline int run_index(ull rs_lo, ull rs_hi, int cs) {
    if (cs < 64)  return __popcll(rs_lo & ((1ULL << cs) - 1ULL));
    if (cs == 64) return __popcll(rs_lo);
    return __popcll(rs_lo) + __popcll(rs_hi & ((1ULL << (cs - 64)) - 1ULL));
}

__device__ inline void top3_ins(float s, int id, int x,
    float& s0, float& s1, float& s2,
    int& i0, int& i1, int& i2,
    int& x0, int& x1, int& x2)
{
    if (x < 0) return;
    if (s > s0 || (s == s0 && id < i0)) {
        s2 = s1; i2 = i1; x2 = x1;
        s1 = s0; i1 = i0; x1 = x0;
        s0 = s;  i0 = id; x0 = x;
    } else if (s > s1 || (s == s1 && id < i1)) {
        s2 = s1; i2 = i1; x2 = x1;
        s1 = s;  i1 = id; x1 = x;
    } else if (s > s2 || (s == s2 && id < i2)) {
        s2 = s;  i2 = id; x2 = x;
    }
}

__device__ inline int aload(const int* p) {
    return __hip_atomic_load(p, __ATOMIC_RELAXED, __HIP_MEMORY_SCOPE_AGENT);
}
__device__ inline float aloadf(const float* p) {
    return __hip_atomic_load(p, __ATOMIC_RELAXED, __HIP_MEMORY_SCOPE_AGENT);
}

// ---------------------------------------------------------------------------
// Kernel 1: one block per 16-row stripe (128 blocks = 8 stripes x 16 images).
// Local run-based union-find CCL + per-component stats in LDS; exports a
// compact component table + boundary-row run->component maps to global.
// R4: the LAST stripe block of each image (detected via a device-scope
// release/acquire counter — ONE fence-bearing atomic per block, not per
// wave; R3 showed grid-wide fencing costs 100s of µs) runs the per-image
// boundary merge inline: unions across the 7 stripe boundaries on an LDS
// parent2, folds stats into root entries via global atomics, top-3 + bbox.
// ---------------------------------------------------------------------------

__global__ __launch_bounds__(256) void stripe_ccl_merge(
    const float* __restrict__ prob,
    int* __restrict__ nlocg, int* __restrict__ gcnt, float* __restrict__ gconf,
    int* __restrict__ gminr, int* __restrict__ gmaxr,
    int* __restrict__ gminc, int* __restrict__ gmaxc,
    int* __restrict__ gmaxid, int* __restrict__ brun, ull* __restrict__ bmask,
    int* __restrict__ imgcnt, int* __restrict__ bbox)
{
    __shared__ ull rowm[SH][2];
    __shared__ unsigned char m8[256];
    __shared__ int parent[NLRUN];          // 4 KB
    __shared__ int   lcnt[SC];
    __shared__ float lconf[SC];
    __shared__ int lminr[SC], lmaxr[SC], lminc[SC], lmaxc[SC], lmaxid[SC];
    __shared__ int snloc;
    __shared__ int parent2[NCI];           // 16 KB (merge phase)
    __shared__ int nl8[NSPI];
    __shared__ int sLast, sK;
    __shared__ float wss[12];
    __shared__ int wid_[12], wrx[12];

    const int g = blockIdx.x;
    const int b = g >> 3, s = g & 7;
    const int row0 = s * SH;
    const int tid = threadIdx.x;
    const int row = tid >> 4;              // 0..15 (stripe-local)
    const int w0 = (tid & 15) * 8;         // 8-col window per thread

    if (tid == 0) snloc = 0;

    // P0: load 8 pixels into registers, build masks
    const float* p = prob + (size_t)b * HW + (size_t)((row0 + row) << 7) + w0;
    vf4 va = *(const vf4*)p;
    vf4 vb = *(const vf4*)(p + 4);
    int mask8 = 0;
    mask8 |= (va.x > 0.5f) << 0; mask8 |= (va.y > 0.5f) << 1;
    mask8 |= (va.z > 0.5f) << 2; mask8 |= (va.w > 0.5f) << 3;
    mask8 |= (vb.x > 0.5f) << 4; mask8 |= (vb.y > 0.5f) << 5;
    mask8 |= (vb.z > 0.5f) << 6; mask8 |= (vb.w > 0.5f) << 7;
    m8[tid] = (unsigned char)mask8;
    for (int j = tid; j < SC; j += 256) {
        lcnt[j] = 0; lconf[j] = 0.f;
        lminr[j] = INT_MAX; lmaxr[j] = -1;
        lminc[j] = INT_MAX; lmaxc[j] = -1;
        lmaxid[j] = 0;
    }
    __syncthreads();
    if (tid < 32) {                        // assemble 64-bit half-row masks
        int r = tid >> 1, half = tid & 1;
        ull v = 0;
        #pragma unroll
        for (int k2 = 0; k2 < 8; ++k2)
            v |= (ull)m8[(r << 4) + (half << 3) + k2] << (k2 * 8);
        rowm[r][half] = v;
    }
    __syncthreads();

    // P1: parent self-init over valid local run ids
    for (int rid = tid; rid < NLRUN; rid += 256) {
        int r = rid >> 6;
        ull lo = rowm[r][0], hi = rowm[r][1];
        ull rs_lo = lo & ~(lo << 1);
        ull rs_hi = hi & ~((hi << 1) | (lo >> 63));
        int nruns = __popcll(rs_lo) + __popcll(rs_hi);
        if ((rid & 63) < nruns) parent[rid] = rid;
    }
    __syncthreads();

    // P2: vertical unions inside the stripe (local rows 1..15)
    for (int i = tid; i < (SH - 1) * 128; i += 256) {
        int r = 1 + (i >> 7), c = i & 127;
        ull lo = rowm[r][0], hi = rowm[r][1];
        if (!getbit2(lo, hi, c)) continue;
        ull ulo = rowm[r - 1][0], uhi = rowm[r - 1][1];
        int l  = (c > 0)   ? getbit2(lo, hi, c - 1) : 0;
        int rt = (c < 127) ? getbit2(lo, hi, c + 1) : 0;
        int up = getbit2(ulo, uhi, c);
        int ul = (c > 0)   ? getbit2(ulo, uhi, c - 1) : 0;
        int ur = (c < 127) ? getbit2(ulo, uhi, c + 1) : 0;
        bool u1 = up && !(l && ul);          // leftmost-contact dedup
        bool u2 = !up && ul && !l;
        bool u3 = !up && ur && !rt;
        if (!(u1 | u2 | u3)) continue;
        ull rs_lo = lo & ~(lo << 1),   rs_hi = hi & ~((hi << 1) | (lo >> 63));
        ull urs_lo = ulo & ~(ulo << 1), urs_hi = uhi & ~((uhi << 1) | (ulo >> 63));
        int cs = run_start_col(lo, hi, c);
        int rid = (r << 6) + run_index(rs_lo, rs_hi, cs);
        int ub = (r - 1) << 6;
        if (u1) uf_union(parent, rid, ub + run_index(urs_lo, urs_hi, run_start_col(ulo, uhi, c)));
        if (u2) uf_union(parent, rid, ub + run_index(urs_lo, urs_hi, run_start_col(ulo, uhi, c - 1)));
        if (u3) uf_union(parent, rid, ub + run_index(urs_lo, urs_hi, run_start_col(ulo, uhi, c + 1)));
    }
    __syncthreads();

    // P3: flatten
    for (int rid = tid; rid < NLRUN; rid += 256) {
        int r = rid >> 6;
        ull lo = rowm[r][0], hi = rowm[r][1];
        ull rs_lo = lo & ~(lo << 1);
        ull rs_hi = hi & ~((hi << 1) | (lo >> 63));
        int nruns = __popcll(rs_lo) + __popcll(rs_hi);
        if ((rid & 63) < nruns) parent[rid] = uf_find(parent, rid);
    }
    __syncthreads();
    // P3b: roots claim dense local indices
    for (int rid = tid; rid < NLRUN; rid += 256) {
        int r = rid >> 6;
        ull lo = rowm[r][0], hi = rowm[r][1];
        ull rs_lo = lo & ~(lo << 1);
        ull rs_hi = hi & ~((hi << 1) | (lo >> 63));
        int nruns = __popcll(rs_lo) + __popcll(rs_hi);
        if ((rid & 63) < nruns && parent[rid] == rid) {
            int idx = atomicAdd(&snloc, 1);
            parent[rid] = NLRUN + idx;
        }
    }
    __syncthreads();

    // P4: per-thread window stats from registers (each pixel counted once)
    {
        ull lo = rowm[row][0], hi = rowm[row][1];
        ull rs_lo = lo & ~(lo << 1);
        ull rs_hi = hi & ~((hi << 1) | (lo >> 63));
        const float vv[8] = {va.x, va.y, va.z, va.w, vb.x, vb.y, vb.z, vb.w};
        const int imr = row0 + row;
        int curIdx = -1, aCnt = 0, aMinc = 0, aMaxc = 0, aMaxid = 0;
        float aConf = 0.f;
        bool prevfg = false;
        #pragma unroll
        for (int j = 0; j < 8; ++j) {
            bool fg = (mask8 >> j) & 1;
            if (fg) {
                int c = w0 + j;
                if (!prevfg) {                 // new window-segment: resolve comp
                    int cs = run_start_col(lo, hi, c);
                    int rid = (row << 6) + run_index(rs_lo, rs_hi, cs);
                    int v = parent[rid];
                    int idx = (v >= NLRUN) ? v - NLRUN : parent[v] - NLRUN;
                    if (idx != curIdx) {
                        if (curIdx >= 0) {
                            atomicAdd(&lcnt[curIdx], aCnt);
                            atomicAdd(&lconf[curIdx], aConf);
                            atomicMin(&lminr[curIdx], imr);
                            atomicMax(&lmaxr[curIdx], imr);
                            atomicMin(&lminc[curIdx], aMinc);
                            atomicMax(&lmaxc[curIdx], aMaxc);
                            atomicMax(&lmaxid[curIdx], aMaxid);
                        }
                        curIdx = idx; aCnt = 0; aConf = 0.f;
                        aMinc = c; aMaxc = c; aMaxid = 0;
                    }
                }
                aCnt++; aConf += vv[j]; aMaxc = c;
                aMaxid = (imr << 7) + c + 1;
            }
            prevfg = fg;
        }
        if (curIdx >= 0) {
            atomicAdd(&lcnt[curIdx], aCnt);
            atomicAdd(&lconf[curIdx], aConf);
            atomicMin(&lminr[curIdx], imr);
            atomicMax(&lmaxr[curIdx], imr);
            atomicMin(&lminc[curIdx], aMinc);
            atomicMax(&lmaxc[curIdx], aMaxc);
            atomicMax(&lmaxid[curIdx], aMaxid);
        }
    }
    __syncthreads();

    // P5: export component table + boundary maps
    const int nl = snloc;
    for (int j = tid; j < nl; j += 256) {
        int d = (g << 9) + j;
        gcnt[d] = lcnt[j];  gconf[d] = lconf[j];
        gminr[d] = lminr[j]; gmaxr[d] = lmaxr[j];
        gminc[d] = lminc[j]; gmaxc[d] = lmaxc[j];
        gmaxid[d] = lmaxid[j];
    }
    if (tid == 0) nlocg[g] = nl;
    if (tid < 128) {
        int br = tid >> 6;                 // 0: local row 0, 1: local row 15
        int j = tid & 63;
        int r = br ? (SH - 1) : 0;
        ull lo = rowm[r][0], hi = rowm[r][1];
        ull rs_lo = lo & ~(lo << 1);
        ull rs_hi = hi & ~((hi << 1) | (lo >> 63));
        int nruns = __popcll(rs_lo) + __popcll(rs_hi);
        if (j < nruns) {
            int rid = (r << 6) + j;
            int v = parent[rid];
            brun[(g << 7) + (br << 6) + j] = (v >= NLRUN) ? v - NLRUN : parent[v] - NLRUN;
        }
        if (j == 0) {
            bmask[(g << 2) + (br << 1) + 0] = lo;
            bmask[(g << 2) + (br << 1) + 1] = hi;
        }
    }
    __syncthreads();   // drains all waves' exports to L2 before the release

    // ---- last-block-done handoff (one release atomic per block) ----
    if (tid == 0) {
        int old = __hip_atomic_fetch_add(&imgcnt[b], 1,
                      __ATOMIC_RELEASE, __HIP_MEMORY_SCOPE_AGENT);
        int last = (old == NSPI - 1);
        if (last)
            (void)__hip_atomic_load(&imgcnt[b],
                      __ATOMIC_ACQUIRE, __HIP_MEMORY_SCOPE_AGENT);
        sLast = last; sK = 0;
    }
    __syncthreads();
    if (!sLast) return;

    // ================= inline merge (one block per image) ==================
    for (int i = tid; i < NCI; i += 256) parent2[i] = i;
    if (tid < NSPI) nl8[tid] = nlocg[(b << 3) + tid];
    __syncthreads();

    // boundary unions: boundary k joins stripe k-1 (row 15) with stripe k
    for (int i = tid; i < 7 * 128; i += 256) {
        int k = 1 + (i >> 7), c = i & 127;
        int gLo = (b << 3) + k, gUp = gLo - 1;
        ull lo = bmask[(gLo << 2) + 0], hi = bmask[(gLo << 2) + 1];
        if (!getbit2(lo, hi, c)) continue;
        ull ulo = bmask[(gUp << 2) + 2], uhi = bmask[(gUp << 2) + 3];
        int l  = (c > 0)   ? getbit2(lo, hi, c - 1) : 0;
        int rt = (c < 127) ? getbit2(lo, hi, c + 1) : 0;
        int up = getbit2(ulo, uhi, c);
        int ul = (c > 0)   ? getbit2(ulo, uhi, c - 1) : 0;
        int ur = (c < 127) ? getbit2(ulo, uhi, c + 1) : 0;
        bool u1 = up && !(l && ul);
        bool u2 = !up && ul && !l;
        bool u3 = !up && ur && !rt;
        if (!(u1 | u2 | u3)) continue;
        ull rs_lo = lo & ~(lo << 1),   rs_hi = hi & ~((hi << 1) | (lo >> 63));
        ull urs_lo = ulo & ~(ulo << 1), urs_hi = uhi & ~((uhi << 1) | (ulo >> 63));
        int cs = run_start_col(lo, hi, c);
        int myid = (k << 9) + brun[(gLo << 7) + run_index(rs_lo, rs_hi, cs)];
        int ubase = (k - 1) << 9;
        if (u1) uf_union(parent2, myid, ubase + brun[(gUp << 7) + 64 + run_index(urs_lo, urs_hi, run_start_col(ulo, uhi, c))]);
        if (u2) uf_union(parent2, myid, ubase + brun[(gUp << 7) + 64 + run_index(urs_lo, urs_hi, run_start_col(ulo, uhi, c - 1))]);
        if (u3) uf_union(parent2, myid, ubase + brun[(gUp << 7) + 64 + run_index(urs_lo, urs_hi, run_start_col(ulo, uhi, c + 1))]);
    }
    __syncthreads();

    // fold non-root stats into root entries (global atomics; targets are
    // always roots, sources always non-roots -> no read/write overlap)
    const int hb = b << 12;   // image base in handle-indexed global arrays
    for (int s2 = 0; s2 < NSPI; ++s2) {
        for (int j = tid; j < nl8[s2]; j += 256) {
            int i = (s2 << 9) + j;
            int r = uf_find(parent2, i);
            if (r != i) {
                atomicAdd(&gcnt[hb + r], gcnt[hb + i]);
                atomicAdd(&gconf[hb + r], gconf[hb + i]);
                atomicMin(&gminr[hb + r], gminr[hb + i]);
                atomicMax(&gmaxr[hb + r], gmaxr[hb + i]);
                atomicMin(&gminc[hb + r], gminc[hb + i]);
                atomicMax(&gmaxc[hb + r], gmaxc[hb + i]);
                atomicMax(&gmaxid[hb + r], gmaxid[hb + i]);
            }
        }
    }
    __syncthreads();

    // top-3 by (mean_conf desc, maxid asc) over roots; K = root count.
    // Root-entry reads use agent-scope atomic loads (bypass possibly-stale L1
    // after the atomic folds).
    float s0 = -INFINITY, s1 = -INFINITY, s2v = -INFINITY;
    int i0 = INT_MAX, i1 = INT_MAX, i2 = INT_MAX;
    int x0 = -1, x1 = -1, x2 = -1;
    int kc = 0;
    for (int s2 = 0; s2 < NSPI; ++s2) {
        for (int j = tid; j < nl8[s2]; j += 256) {
            int i = (s2 << 9) + j;
            if (parent2[i] == i) {
                ++kc;
                float sc = aloadf(&gconf[hb + i]) / (float)aload(&gcnt[hb + i]);
                top3_ins(sc, aload(&gmaxid[hb + i]), i,
                         s0, s1, s2v, i0, i1, i2, x0, x1, x2);
            }
        }
    }
    for (int off = 32; off; off >>= 1) kc += __shfl_xor(kc, off);
    if ((tid & 63) == 0) atomicAdd(&sK, kc);
    for (int off = 32; off; off >>= 1) {
        float bs0 = __shfl_xor(s0, off), bs1 = __shfl_xor(s1, off), bs2 = __shfl_xor(s2v, off);
        int bi0 = __shfl_xor(i0, off), bi1 = __shfl_xor(i1, off), bi2 = __shfl_xor(i2, off);
        int bx0 = __shfl_xor(x0, off), bx1 = __shfl_xor(x1, off), bx2 = __shfl_xor(x2, off);
        top3_ins(bs0, bi0, bx0, s0, s1, s2v, i0, i1, i2, x0, x1, x2);
        top3_ins(bs1, bi1, bx1, s0, s1, s2v, i0, i1, i2, x0, x1, x2);
        top3_ins(bs2, bi2, bx2, s0, s1, s2v, i0, i1, i2, x0, x1, x2);
    }
    if ((tid & 63) == 0) {
        int w = tid >> 6;
        wss[w * 3 + 0] = s0; wid_[w * 3 + 0] = i0; wrx[w * 3 + 0] = x0;
        wss[w * 3 + 1] = s1; wid_[w * 3 + 1] = i1; wrx[w * 3 + 1] = x1;
        wss[w * 3 + 2] = s2v; wid_[w * 3 + 2] = i2; wrx[w * 3 + 2] = x2;
    }
    __syncthreads();

    if (tid == 0) {
        float t0 = -INFINITY, t1 = -INFINITY, t2 = -INFINITY;
        int ti0 = INT_MAX, ti1 = INT_MAX, ti2 = INT_MAX;
        int tx0 = -1, tx1 = -1, tx2 = -1;
        for (int t = 0; t < 12; ++t)
            top3_ins(wss[t], wid_[t], wrx[t], t0, t1, t2, ti0, ti1, ti2, tx0, tx1, tx2);
        int K = sK;
        int roots[3];
        if (K >= 3)      { roots[0] = tx0; roots[1] = tx1; roots[2] = tx2; }
        else if (K == 2) { roots[0] = tx0; roots[1] = tx0; roots[2] = tx1; }
        else             { roots[0] = tx0; roots[1] = tx0; roots[2] = tx0; }
        for (int slot = 0; slot < 3; ++slot) {
            int mr, h, mc, w;
            if (K == 0) { mr = 0; h = HH; mc = 0; w = WW_; }
            else {
                int rt = roots[slot];
                mr = aload(&gminr[hb + rt]); h = aload(&gmaxr[hb + rt]) + 1 - mr;
                mc = aload(&gminc[hb + rt]); w = aload(&gmaxc[hb + rt]) + 1 - mc;
            }
            int* o = bbox + (b * 3 + slot) * 4;
            o[0] = mr; o[1] = h; o[2] = mc; o[3] = w;
        }
    }
}

// ---------------------------------------------------------------------------
// Kernel 2: nearest-neighbor crop-resize gather. 1024-thr blocks, 4
// independent float4 NT stores per thread (16x fewer workgroups than the
// 256-thr one-store version; 4-deep MLP).
// ---------------------------------------------------------------------------

__global__ __launch_bounds__(1024) void crop_kernel(
    const float* __restrict__ feat, const int* __restrict__ bbox,
    float* __restrict__ out)
{
    const int base = blockIdx.x * 1024 + threadIdx.x;
    #pragma unroll
    for (int k = 0; k < 4; ++k) {
        const int gid = base + k * (CROP_BLKS * 1024);
        const int x4 = gid & 15;
        const int y  = (gid >> 4) & 63;
        const int t  = gid >> 10;        // (b*3+slot)*192 + c, 0..9215
        const int c  = t % CF;
        const int bs = t / CF;           // b*3+slot, 0..47
        const int* bb = bbox + bs * 4;
        const int mr = bb[0], h = bb[1], mc = bb[2], w = bb[3];
        const int r = mr + ((y * h) >> 6);
        const int bimg = bs / 3;
        const float* row = feat + (((size_t)bimg * CF + c) * HH + r) * WW_;
        const int x = x4 * 4;
        vf4 v;
        v.x = row[mc + (((x + 0) * w) >> 6)];
        v.y = row[mc + (((x + 1) * w) >> 6)];
        v.z = row[mc + (((x + 2) * w) >> 6)];
        v.w = row[mc + (((x + 3) * w) >> 6)];
        __builtin_nontemporal_store(v, (vf4*)out + gid);  // streaming store
    }
}

// ---------------------------------------------------------------------------

extern "C" void kernel_launch(void* const* d_in, const int* in_sizes, int n_in,
                              void* d_out, int out_size, void* d_ws, size_t ws_size,
                              hipStream_t stream) {
    const float* prob = (const float*)d_in[0];   // [16,1,128,128]
    const float* feat = (const float*)d_in[1];   // [16,192,128,128]
    float* out = (float*)d_out;                  // [16,576,64,64]

    int* ws = (int*)d_ws;
    int* bbox   = ws;                            // 192 ints
    int* nlocg  = ws + 192;                      // 128
    int* gcnt   = ws + 320;                      // 7 arrays x 128*512
    float* gconf = (float*)(ws + 320 + 1 * 65536);
    int* gminr  = ws + 320 + 2 * 65536;
    int* gmaxr  = ws + 320 + 3 * 65536;
    int* gminc  = ws + 320 + 4 * 65536;
    int* gmaxc  = ws + 320 + 5 * 65536;
    int* gmaxid = ws + 320 + 6 * 65536;
    int* brun   = ws + 320 + 7 * 65536;          // 128*2*64
    ull* bmask  = (ull*)(ws + 320 + 7 * 65536 + 16384);  // 128*2*2 ulls
    int* imgcnt = ws + 320 + 7 * 65536 + 16384 + 1024;   // 16 ints

    // zero the per-image completion counters (ws is re-poisoned every iter)
    hipMemsetAsync(imgcnt, 0, NB * sizeof(int), stream);

    hipLaunchKernelGGL(stripe_ccl_merge, dim3(NST), dim3(256), 0, stream,
                       prob, nlocg, gcnt, gconf, gminr, gmaxr, gminc, gmaxc,
                       gmaxid, brun, bmask, imgcnt, bbox);
    hipLaunchKernelGGL(crop_kernel, dim3(CROP_BLKS), dim3(1024), 0, stream,
                       feat, bbox, out);
}

// Round 5
// 344.307 us; speedup vs baseline: 1.8135x; 1.0789x over previous
//
#include <hip/hip_runtime.h>
#include <limits.h>

#define HH 128
#define WW_ 128
#define HW 16384
#define NB 16
#define CF 192
#define H2 64
#define W2 64

#define SH 16          // stripe height
#define NSPI 8         // stripes per image
#define NST 128        // total stripe blocks
#define SC 512         // max components per 16x128 stripe
#define NCI 4096       // component handles per image = NSPI*SC
#define NLRUN 1024     // local run-id slots = SH*64

#define CB_CH 16       // channels per crop block
#define CROP_BLKS (NB * 3 * (CF / CB_CH))   // 48 * 12 = 576

typedef float vf4 __attribute__((ext_vector_type(4)));
typedef unsigned long long ull;

// ---------------------------------------------------------------------------
// Union-find on an LDS parent array. Links always go high->low id -> chains
// strictly decrease -> concurrent path halving is safe and terminating.
// ---------------------------------------------------------------------------

__device__ inline int uf_find(int* par, int x) {
    volatile int* vp = (volatile int*)par;
    int p = vp[x];
    while (p != x) {
        int g = vp[p];
        vp[x] = g;      // path halving: writes an ancestor, safe under races
        x = g;
        p = vp[x];
    }
    return x;
}

__device__ inline void uf_union(int* par, int a, int b) {
    int ra = uf_find(par, a);
    int rb = uf_find(par, b);
    while (ra != rb) {
        if (ra < rb) { int t = ra; ra = rb; rb = t; }   // link larger -> smaller
        int old = atomicCAS(&par[ra], ra, rb);
        if (old == ra) return;
        ra = uf_find(par, old);
        rb = uf_find(par, rb);
    }
}

// ---------------------------------------------------------------------------
// 128-bit row mask helpers (lo = cols 0..63, hi = cols 64..127)
// ---------------------------------------------------------------------------

__device__ inline int getbit2(ull lo, ull hi, int c) {
    return (int)(((c < 64) ? (lo >> c) : (hi >> (c - 64))) & 1ULL);
}

__device__ inline int leading_ones(ull v) {
    ull nv = ~v;
    return (nv == 0ULL) ? 64 : __clzll(nv);
}

// column of the start of the fg run containing column c (bit c must be set)
__device__ inline int run_start_col(ull lo, ull hi, int c) {
    if (c < 64) {
        int ones = leading_ones(lo << (63 - c));   // consecutive ones ending at c
        return c - ones + 1;
    }
    int ones = leading_ones(hi << (127 - c));
    int rs = c - ones + 1;
    if (rs == 64) rs -= leading_ones(lo);          // run crosses the 64 boundary
    return rs;
}

// 0-based index of the run starting at column cs (cs must be a run start)
__device__ inline int run_index(ull rs_lo, ull rs_hi, int cs) {
    if (cs < 64)  return __popcll(rs_lo & ((1ULL << cs) - 1ULL));
    if (cs == 64) return __popcll(rs_lo);
    return __popcll(rs_lo) + __popcll(rs_hi & ((1ULL << (cs - 64)) - 1ULL));
}

__device__ inline void top3_ins(float s, int id, int x,
    float& s0, float& s1, float& s2,
    int& i0, int& i1, int& i2,
    int& x0, int& x1, int& x2)
{
    if (x < 0) return;
    if (s > s0 || (s == s0 && id < i0)) {
        s2 = s1; i2 = i1; x2 = x1;
        s1 = s0; i1 = i0; x1 = x0;
        s0 = s;  i0 = id; x0 = x;
    } else if (s > s1 || (s == s1 && id < i1)) {
        s2 = s1; i2 = i1; x2 = x1;
        s1 = s;  i1 = id; x1 = x;
    } else if (s > s2 || (s == s2 && id < i2)) {
        s2 = s;  i2 = id; x2 = x;
    }
}

// ---------------------------------------------------------------------------
// Kernel A: one block per 16-row stripe (128 blocks = 8 stripes x 16 images).
// (Identical to the verified R2 version.)
// ---------------------------------------------------------------------------

__global__ __launch_bounds__(256) void stripe_ccl(
    const float* __restrict__ prob,
    int* __restrict__ nlocg, int* __restrict__ gcnt, float* __restrict__ gconf,
    int* __restrict__ gminr, int* __restrict__ gmaxr,
    int* __restrict__ gminc, int* __restrict__ gmaxc,
    int* __restrict__ gmaxid, int* __restrict__ brun, ull* __restrict__ bmask)
{
    __shared__ ull rowm[SH][2];            // 256 B
    __shared__ unsigned char m8[256];      // per-thread 8-px masks
    __shared__ int parent[NLRUN];          // 4 KB
    __shared__ int   lcnt[SC];             // per-component stats: 14 KB total
    __shared__ float lconf[SC];
    __shared__ int lminr[SC], lmaxr[SC], lminc[SC], lmaxc[SC], lmaxid[SC];
    __shared__ int snloc;

    const int g = blockIdx.x;
    const int b = g >> 3, s = g & 7;
    const int row0 = s * SH;
    const int tid = threadIdx.x;
    const int row = tid >> 4;              // 0..15 (stripe-local)
    const int w0 = (tid & 15) * 8;         // 8-col window per thread

    if (tid == 0) snloc = 0;

    // P0: load 8 pixels into registers, build masks
    const float* p = prob + (size_t)b * HW + (size_t)((row0 + row) << 7) + w0;
    vf4 va = *(const vf4*)p;
    vf4 vb = *(const vf4*)(p + 4);
    int mask8 = 0;
    mask8 |= (va.x > 0.5f) << 0; mask8 |= (va.y > 0.5f) << 1;
    mask8 |= (va.z > 0.5f) << 2; mask8 |= (va.w > 0.5f) << 3;
    mask8 |= (vb.x > 0.5f) << 4; mask8 |= (vb.y > 0.5f) << 5;
    mask8 |= (vb.z > 0.5f) << 6; mask8 |= (vb.w > 0.5f) << 7;
    m8[tid] = (unsigned char)mask8;
    for (int j = tid; j < SC; j += 256) {
        lcnt[j] = 0; lconf[j] = 0.f;
        lminr[j] = INT_MAX; lmaxr[j] = -1;
        lminc[j] = INT_MAX; lmaxc[j] = -1;
        lmaxid[j] = 0;
    }
    __syncthreads();
    if (tid < 32) {                        // assemble 64-bit half-row masks
        int r = tid >> 1, half = tid & 1;
        ull v = 0;
        #pragma unroll
        for (int k2 = 0; k2 < 8; ++k2)
            v |= (ull)m8[(r << 4) + (half << 3) + k2] << (k2 * 8);
        rowm[r][half] = v;
    }
    __syncthreads();

    // P1: parent self-init over valid local run ids
    for (int rid = tid; rid < NLRUN; rid += 256) {
        int r = rid >> 6;
        ull lo = rowm[r][0], hi = rowm[r][1];
        ull rs_lo = lo & ~(lo << 1);
        ull rs_hi = hi & ~((hi << 1) | (lo >> 63));
        int nruns = __popcll(rs_lo) + __popcll(rs_hi);
        if ((rid & 63) < nruns) parent[rid] = rid;
    }
    __syncthreads();

    // P2: vertical unions inside the stripe (local rows 1..15)
    for (int i = tid; i < (SH - 1) * 128; i += 256) {
        int r = 1 + (i >> 7), c = i & 127;
        ull lo = rowm[r][0], hi = rowm[r][1];
        if (!getbit2(lo, hi, c)) continue;
        ull ulo = rowm[r - 1][0], uhi = rowm[r - 1][1];
        int l  = (c > 0)   ? getbit2(lo, hi, c - 1) : 0;
        int rt = (c < 127) ? getbit2(lo, hi, c + 1) : 0;
        int up = getbit2(ulo, uhi, c);
        int ul = (c > 0)   ? getbit2(ulo, uhi, c - 1) : 0;
        int ur = (c < 127) ? getbit2(ulo, uhi, c + 1) : 0;
        bool u1 = up && !(l && ul);          // leftmost-contact dedup
        bool u2 = !up && ul && !l;
        bool u3 = !up && ur && !rt;
        if (!(u1 | u2 | u3)) continue;
        ull rs_lo = lo & ~(lo << 1),   rs_hi = hi & ~((hi << 1) | (lo >> 63));
        ull urs_lo = ulo & ~(ulo << 1), urs_hi = uhi & ~((uhi << 1) | (ulo >> 63));
        int cs = run_start_col(lo, hi, c);
        int rid = (r << 6) + run_index(rs_lo, rs_hi, cs);
        int ub = (r - 1) << 6;
        if (u1) uf_union(parent, rid, ub + run_index(urs_lo, urs_hi, run_start_col(ulo, uhi, c)));
        if (u2) uf_union(parent, rid, ub + run_index(urs_lo, urs_hi, run_start_col(ulo, uhi, c - 1)));
        if (u3) uf_union(parent, rid, ub + run_index(urs_lo, urs_hi, run_start_col(ulo, uhi, c + 1)));
    }
    __syncthreads();

    // P3: flatten
    for (int rid = tid; rid < NLRUN; rid += 256) {
        int r = rid >> 6;
        ull lo = rowm[r][0], hi = rowm[r][1];
        ull rs_lo = lo & ~(lo << 1);
        ull rs_hi = hi & ~((hi << 1) | (lo >> 63));
        int nruns = __popcll(rs_lo) + __popcll(rs_hi);
        if ((rid & 63) < nruns) parent[rid] = uf_find(parent, rid);
    }
    __syncthreads();
    // P3b: roots claim dense local indices
    for (int rid = tid; rid < NLRUN; rid += 256) {
        int r = rid >> 6;
        ull lo = rowm[r][0], hi = rowm[r][1];
        ull rs_lo = lo & ~(lo << 1);
        ull rs_hi = hi & ~((hi << 1) | (lo >> 63));
        int nruns = __popcll(rs_lo) + __popcll(rs_hi);
        if ((rid & 63) < nruns && parent[rid] == rid) {
            int idx = atomicAdd(&snloc, 1);
            parent[rid] = NLRUN + idx;
        }
    }
    __syncthreads();

    // P4: per-thread window stats from registers (each pixel counted once)
    {
        ull lo = rowm[row][0], hi = rowm[row][1];
        ull rs_lo = lo & ~(lo << 1);
        ull rs_hi = hi & ~((hi << 1) | (lo >> 63));
        const float vv[8] = {va.x, va.y, va.z, va.w, vb.x, vb.y, vb.z, vb.w};
        const int imr = row0 + row;
        int curIdx = -1, aCnt = 0, aMinc = 0, aMaxc = 0, aMaxid = 0;
        float aConf = 0.f;
        bool prevfg = false;
        #pragma unroll
        for (int j = 0; j < 8; ++j) {
            bool fg = (mask8 >> j) & 1;
            if (fg) {
                int c = w0 + j;
                if (!prevfg) {                 // new window-segment: resolve comp
                    int cs = run_start_col(lo, hi, c);
                    int rid = (row << 6) + run_index(rs_lo, rs_hi, cs);
                    int v = parent[rid];
                    int idx = (v >= NLRUN) ? v - NLRUN : parent[v] - NLRUN;
                    if (idx != curIdx) {
                        if (curIdx >= 0) {
                            atomicAdd(&lcnt[curIdx], aCnt);
                            atomicAdd(&lconf[curIdx], aConf);
                            atomicMin(&lminr[curIdx], imr);
                            atomicMax(&lmaxr[curIdx], imr);
                            atomicMin(&lminc[curIdx], aMinc);
                            atomicMax(&lmaxc[curIdx], aMaxc);
                            atomicMax(&lmaxid[curIdx], aMaxid);
                        }
                        curIdx = idx; aCnt = 0; aConf = 0.f;
                        aMinc = c; aMaxc = c; aMaxid = 0;
                    }
                }
                aCnt++; aConf += vv[j]; aMaxc = c;
                aMaxid = (imr << 7) + c + 1;
            }
            prevfg = fg;
        }
        if (curIdx >= 0) {
            atomicAdd(&lcnt[curIdx], aCnt);
            atomicAdd(&lconf[curIdx], aConf);
            atomicMin(&lminr[curIdx], imr);
            atomicMax(&lmaxr[curIdx], imr);
            atomicMin(&lminc[curIdx], aMinc);
            atomicMax(&lmaxc[curIdx], aMaxc);
            atomicMax(&lmaxid[curIdx], aMaxid);
        }
    }
    __syncthreads();

    // P5: export component table + boundary maps
    const int nl = snloc;
    for (int j = tid; j < nl; j += 256) {
        int d = (g << 9) + j;
        gcnt[d] = lcnt[j];  gconf[d] = lconf[j];
        gminr[d] = lminr[j]; gmaxr[d] = lmaxr[j];
        gminc[d] = lminc[j]; gmaxc[d] = lmaxc[j];
        gmaxid[d] = lmaxid[j];
    }
    if (tid == 0) nlocg[g] = nl;
    if (tid < 128) {
        int br = tid >> 6;                 // 0: local row 0, 1: local row 15
        int j = tid & 63;
        int r = br ? (SH - 1) : 0;
        ull lo = rowm[r][0], hi = rowm[r][1];
        ull rs_lo = lo & ~(lo << 1);
        ull rs_hi = hi & ~((hi << 1) | (lo >> 63));
        int nruns = __popcll(rs_lo) + __popcll(rs_hi);
        if (j < nruns) {
            int rid = (r << 6) + j;
            int v = parent[rid];
            brun[(g << 7) + (br << 6) + j] = (v >= NLRUN) ? v - NLRUN : parent[v] - NLRUN;
        }
        if (j == 0) {
            bmask[(g << 2) + (br << 1) + 0] = lo;
            bmask[(g << 2) + (br << 1) + 1] = hi;
        }
    }
}

// ---------------------------------------------------------------------------
// Kernel B: one block per image. (Identical to the verified R2 version.)
// ---------------------------------------------------------------------------

__global__ __launch_bounds__(1024) void merge_kernel(
    const int* __restrict__ nlocg, const int* __restrict__ gcnt,
    const float* __restrict__ gconf,
    const int* __restrict__ gminr, const int* __restrict__ gmaxr,
    const int* __restrict__ gminc, const int* __restrict__ gmaxc,
    const int* __restrict__ gmaxid, const int* __restrict__ brun,
    const ull* __restrict__ bmask, int* __restrict__ bbox)
{
    __shared__ int parent2[NCI];          // 16 KB
    __shared__ int   cnt2[NCI];           // 7 x 16 KB stats
    __shared__ float conf2[NCI];
    __shared__ int minr2[NCI], maxr2[NCI], minc2[NCI], maxc2[NCI], maxid2[NCI];
    __shared__ int sK;
    __shared__ float wss[48];
    __shared__ int wid_[48], wrx[48];

    const int b = blockIdx.x;
    const int tid = threadIdx.x;
    if (tid == 0) sK = 0;
    for (int i = tid; i < NCI; i += 1024) { parent2[i] = i; cnt2[i] = 0; }
    __syncthreads();

    // load stripe component tables into handle space s*512+j
    for (int s = 0; s < NSPI; ++s) {
        int g = (b << 3) + s;
        int n = nlocg[g];
        for (int j = tid; j < n; j += 1024) {
            int d = (s << 9) + j, e = (g << 9) + j;
            cnt2[d] = gcnt[e];  conf2[d] = gconf[e];
            minr2[d] = gminr[e]; maxr2[d] = gmaxr[e];
            minc2[d] = gminc[e]; maxc2[d] = gmaxc[e];
            maxid2[d] = gmaxid[e];
        }
    }
    __syncthreads();

    // boundary unions: boundary k joins stripe k-1 (its row 15) with stripe k
    // (its row 0) at image row 16k
    for (int i = tid; i < 7 * 128; i += 1024) {
        int k = 1 + (i >> 7), c = i & 127;
        int gLo = (b << 3) + k, gUp = gLo - 1;
        ull lo = bmask[(gLo << 2) + 0], hi = bmask[(gLo << 2) + 1];
        if (!getbit2(lo, hi, c)) continue;
        ull ulo = bmask[(gUp << 2) + 2], uhi = bmask[(gUp << 2) + 3];
        int l  = (c > 0)   ? getbit2(lo, hi, c - 1) : 0;
        int rt = (c < 127) ? getbit2(lo, hi, c + 1) : 0;
        int up = getbit2(ulo, uhi, c);
        int ul = (c > 0)   ? getbit2(ulo, uhi, c - 1) : 0;
        int ur = (c < 127) ? getbit2(ulo, uhi, c + 1) : 0;
        bool u1 = up && !(l && ul);
        bool u2 = !up && ul && !l;
        bool u3 = !up && ur && !rt;
        if (!(u1 | u2 | u3)) continue;
        ull rs_lo = lo & ~(lo << 1),   rs_hi = hi & ~((hi << 1) | (lo >> 63));
        ull urs_lo = ulo & ~(ulo << 1), urs_hi = uhi & ~((uhi << 1) | (ulo >> 63));
        int cs = run_start_col(lo, hi, c);
        int myid = (k << 9) + brun[(gLo << 7) + run_index(rs_lo, rs_hi, cs)];
        int ubase = (k - 1) << 9;
        if (u1) uf_union(parent2, myid, ubase + brun[(gUp << 7) + 64 + run_index(urs_lo, urs_hi, run_start_col(ulo, uhi, c))]);
        if (u2) uf_union(parent2, myid, ubase + brun[(gUp << 7) + 64 + run_index(urs_lo, urs_hi, run_start_col(ulo, uhi, c - 1))]);
        if (u3) uf_union(parent2, myid, ubase + brun[(gUp << 7) + 64 + run_index(urs_lo, urs_hi, run_start_col(ulo, uhi, c + 1))]);
    }
    __syncthreads();

    // fold non-root stats into roots (forest fixed; merges target roots only)
    for (int i = tid; i < NCI; i += 1024) {
        if (cnt2[i] > 0) {
            int r = uf_find(parent2, i);
            if (r != i) {
                atomicAdd(&cnt2[r], cnt2[i]);   atomicAdd(&conf2[r], conf2[i]);
                atomicMin(&minr2[r], minr2[i]); atomicMax(&maxr2[r], maxr2[i]);
                atomicMin(&minc2[r], minc2[i]); atomicMax(&maxc2[r], maxc2[i]);
                atomicMax(&maxid2[r], maxid2[i]);
            }
        }
    }
    __syncthreads();

    // top-3 by (mean_conf desc, id asc) over roots; K = root count
    float s0 = -INFINITY, s1 = -INFINITY, s2 = -INFINITY;
    int i0 = INT_MAX, i1 = INT_MAX, i2 = INT_MAX;
    int x0 = -1, x1 = -1, x2 = -1;
    int kc = 0;
    for (int i = tid; i < NCI; i += 1024) {
        if (parent2[i] == i && cnt2[i] > 0) {
            ++kc;
            float sc = conf2[i] / (float)cnt2[i];
            top3_ins(sc, maxid2[i], i, s0, s1, s2, i0, i1, i2, x0, x1, x2);
        }
    }
    for (int off = 32; off; off >>= 1) kc += __shfl_xor(kc, off);
    if ((tid & 63) == 0) atomicAdd(&sK, kc);
    for (int off = 32; off; off >>= 1) {
        float bs0 = __shfl_xor(s0, off), bs1 = __shfl_xor(s1, off), bs2 = __shfl_xor(s2, off);
        int bi0 = __shfl_xor(i0, off), bi1 = __shfl_xor(i1, off), bi2 = __shfl_xor(i2, off);
        int bx0 = __shfl_xor(x0, off), bx1 = __shfl_xor(x1, off), bx2 = __shfl_xor(x2, off);
        top3_ins(bs0, bi0, bx0, s0, s1, s2, i0, i1, i2, x0, x1, x2);
        top3_ins(bs1, bi1, bx1, s0, s1, s2, i0, i1, i2, x0, x1, x2);
        top3_ins(bs2, bi2, bx2, s0, s1, s2, i0, i1, i2, x0, x1, x2);
    }
    if ((tid & 63) == 0) {
        int w = tid >> 6;
        wss[w * 3 + 0] = s0; wid_[w * 3 + 0] = i0; wrx[w * 3 + 0] = x0;
        wss[w * 3 + 1] = s1; wid_[w * 3 + 1] = i1; wrx[w * 3 + 1] = x1;
        wss[w * 3 + 2] = s2; wid_[w * 3 + 2] = i2; wrx[w * 3 + 2] = x2;
    }
    __syncthreads();

    if (tid == 0) {
        float t0 = -INFINITY, t1 = -INFINITY, t2 = -INFINITY;
        int ti0 = INT_MAX, ti1 = INT_MAX, ti2 = INT_MAX;
        int tx0 = -1, tx1 = -1, tx2 = -1;
        for (int t = 0; t < 48; ++t)
            top3_ins(wss[t], wid_[t], wrx[t], t0, t1, t2, ti0, ti1, ti2, tx0, tx1, tx2);
        int K = sK;
        int roots[3];
        if (K >= 3)      { roots[0] = tx0; roots[1] = tx1; roots[2] = tx2; }
        else if (K == 2) { roots[0] = tx0; roots[1] = tx0; roots[2] = tx1; }
        else             { roots[0] = tx0; roots[1] = tx0; roots[2] = tx0; }
        for (int slot = 0; slot < 3; ++slot) {
            int mr, h, mc, w;
            if (K == 0) { mr = 0; h = HH; mc = 0; w = WW_; }
            else {
                int rt = roots[slot];
                mr = minr2[rt]; h = maxr2[rt] + 1 - mr;
                mc = minc2[rt]; w = maxc2[rt] + 1 - mc;
            }
            int* o = bbox + (b * 3 + slot) * 4;
            o[0] = mr; o[1] = h; o[2] = mc; o[3] = w;
        }
    }
}

// ---------------------------------------------------------------------------
// Kernel C (R5 redesign): crop gather with channel-amortized index math.
// Block = (bs, 16-channel chunk); thread = (y, x4). The source row r and the
// 4 source-column offsets depend only on (bs,y,x) -> computed ONCE per
// thread as 32-bit voffsets against a wave-uniform base (feat < 4 GB), then
// the 16-channel loop is ~2 SALU + 4 loads + 1 NT store per float4.
// Old version recomputed ~15-18 VALU ops per float4 x 9.4M threads
// (~70-90 us, the dominant controllable cost).
// ---------------------------------------------------------------------------

__global__ __launch_bounds__(1024) void crop_kernel(
    const float* __restrict__ feat, const int* __restrict__ bbox,
    float* __restrict__ out)
{
    const int blk = blockIdx.x;          // 0..575
    const int bs  = blk / (CF / CB_CH);  // 0..47  (b*3+slot)
    const int cq  = blk % (CF / CB_CH);  // channel chunk
    const int c0  = cq * CB_CH;
    const int tid = threadIdx.x;
    const int y   = tid >> 4;            // 0..63
    const int x4  = tid & 15;            // 0..15

    const int* bb = bbox + bs * 4;       // wave-uniform -> scalarized
    const int mr = bb[0], h = bb[1], mc = bb[2], w = bb[3];
    const int bimg = bs / 3;

    const int r = mr + ((y * h) >> 6);
    const int x = x4 * 4;
    // 32-bit element offsets within the (bimg, c) feature plane
    const int o0 = (r << 7) + mc + (((x + 0) * w) >> 6);
    const int o1 = (r << 7) + mc + (((x + 1) * w) >> 6);
    const int o2 = (r << 7) + mc + (((x + 2) * w) >> 6);
    const int o3 = (r << 7) + mc + (((x + 3) * w) >> 6);

    const float* base = feat + ((size_t)bimg * CF + c0) * HW;       // uniform
    vf4* o4 = (vf4*)out + ((size_t)(bs * CF + c0) * H2 + y) * 16 + x4;

    #pragma unroll
    for (int ci = 0; ci < CB_CH; ++ci) {
        const float* rp = base + (size_t)ci * HW;   // uniform base + u32 voffs
        vf4 v;
        v.x = rp[o0];
        v.y = rp[o1];
        v.z = rp[o2];
        v.w = rp[o3];
        __builtin_nontemporal_store(v, o4 + ci * (H2 * 16));  // streaming store
    }
}

// ---------------------------------------------------------------------------

extern "C" void kernel_launch(void* const* d_in, const int* in_sizes, int n_in,
                              void* d_out, int out_size, void* d_ws, size_t ws_size,
                              hipStream_t stream) {
    const float* prob = (const float*)d_in[0];   // [16,1,128,128]
    const float* feat = (const float*)d_in[1];   // [16,192,128,128]
    float* out = (float*)d_out;                  // [16,576,64,64]

    int* ws = (int*)d_ws;
    int* bbox   = ws;                            // 192 ints
    int* nlocg  = ws + 192;                      // 128
    int* gcnt   = ws + 320;                      // 7 arrays x 128*512
    float* gconf = (float*)(ws + 320 + 1 * 65536);
    int* gminr  = ws + 320 + 2 * 65536;
    int* gmaxr  = ws + 320 + 3 * 65536;
    int* gminc  = ws + 320 + 4 * 65536;
    int* gmaxc  = ws + 320 + 5 * 65536;
    int* gmaxid = ws + 320 + 6 * 65536;
    int* brun   = ws + 320 + 7 * 65536;          // 128*2*64
    ull* bmask  = (ull*)(ws + 320 + 7 * 65536 + 16384);  // 128*2*2 ulls

    hipLaunchKernelGGL(stripe_ccl, dim3(NST), dim3(256), 0, stream,
                       prob, nlocg, gcnt, gconf, gminr, gmaxr, gminc, gmaxc,
                       gmaxid, brun, bmask);
    hipLaunchKernelGGL(merge_kernel, dim3(NB), dim3(1024), 0, stream,
                       nlocg, gcnt, gconf, gminr, gmaxr, gminc, gmaxc,
                       gmaxid, brun, bmask, bbox);
    hipLaunchKernelGGL(crop_kernel, dim3(CROP_BLKS), dim3(1024), 0, stream,
                       feat, bbox, out);
}